// Round 1
// baseline (2429.297 us; speedup 1.0000x reference)
//
#include <hip/hip_runtime.h>
#include <hip/hip_bf16.h>

// Problem constants
#define TOTAL     131072
#define DIMV      690
#define DP        692          // padded LDS row stride (16B-aligned rows)
#define NCLASS    53
#define NTYPE     324
#define NCOLS     377          // NTYPE + NCLASS
#define NBAGS     8192
#define ROWS      16           // rows per block in main kernel
#define ZSTRIDE   384          // z-tile row stride in LDS
#define ALPHA     0.9f

// ---------------------------------------------------------------------------
// Kernel 0: table[s][q] = dot(type_weight[s], relation_weight[q])  (324 x 53)
// one wave per (s,q) pair
// ---------------------------------------------------------------------------
__global__ __launch_bounds__(256) void k_table(const float* __restrict__ tw,
                                               const float* __restrict__ rw,
                                               float* __restrict__ table) {
    const int pair = blockIdx.x * 4 + (threadIdx.x >> 6);
    const int lane = threadIdx.x & 63;
    if (pair >= NTYPE * NCLASS) return;
    const int s = pair / NCLASS;
    const int q = pair % NCLASS;
    const float* a = tw + (size_t)s * DIMV;
    const float* b = rw + (size_t)q * DIMV;
    float acc = 0.f;
    for (int k = lane; k < DIMV; k += 64) acc += a[k] * b[k];
#pragma unroll
    for (int off = 32; off; off >>= 1) acc += __shfl_xor(acc, off);
    if (lane == 0) table[pair] = acc;
}

// ---------------------------------------------------------------------------
// Kernel 1: main fused kernel.
//   per block: 16 sentence rows.
//   Phase A: stage x[16][690] to LDS.
//   Phase B: z[16][377] = x_tile @ [liner_w | rel_w].T   (fp32 FMA)
//   Phase C: per-row softmax over first 324 cols -> type_logits,
//            argmax(nscore) -> soft_label, att = z[324+q] + table[s][q],
//            xr row = z[324..377)
// ---------------------------------------------------------------------------
__global__ __launch_bounds__(256) void k_main(const float* __restrict__ x,
                                              const int* __restrict__ type_label,
                                              const int* __restrict__ query,
                                              const float* __restrict__ rel_w,
                                              const float* __restrict__ liner_w,
                                              const float* __restrict__ liner_b,
                                              const float* __restrict__ table,
                                              float* __restrict__ type_logits,
                                              float* __restrict__ att,
                                              float* __restrict__ xr) {
    __shared__ float sbuf[ROWS * DP];   // 44288 B; reused as z-tile [ROWS][ZSTRIDE]
    const int tid  = threadIdx.x;
    const int base = blockIdx.x * ROWS;

    // ---- Phase A: stage x tile (rows are contiguous; float2 coalesced) ----
    for (int r = 0; r < ROWS; ++r) {
        const float2* src = (const float2*)(x + (size_t)(base + r) * DIMV);
        float2* dst = (float2*)&sbuf[r * DP];
        for (int k = tid; k < DIMV / 2; k += 256) dst[k] = src[k];
    }
    __syncthreads();

    // ---- Phase B: GEMM. thread owns cols c0=tid and c1=tid+256 (if <377) ----
    const int c0 = tid;
    const int c1 = tid + 256;
    const bool have1 = (c1 < NCOLS);
    const float* W0 = (c0 < NTYPE) ? (liner_w + (size_t)c0 * DIMV)
                                   : (rel_w + (size_t)(c0 - NTYPE) * DIMV);
    const float* W1 = have1 ? ((c1 < NTYPE) ? (liner_w + (size_t)c1 * DIMV)
                                            : (rel_w + (size_t)(c1 - NTYPE) * DIMV))
                            : W0;

    float a0[ROWS], a1[ROWS];
#pragma unroll
    for (int r = 0; r < ROWS; ++r) { a0[r] = 0.f; a1[r] = 0.f; }

    int k = 0;
    for (; k + 4 <= DIMV; k += 4) {
        float4 xv[ROWS];
#pragma unroll
        for (int r = 0; r < ROWS; ++r) xv[r] = *(const float4*)&sbuf[r * DP + k];
        {
            const float2 wa = *(const float2*)(W0 + k);
            const float2 wb = *(const float2*)(W0 + k + 2);
#pragma unroll
            for (int r = 0; r < ROWS; ++r) {
                a0[r] = fmaf(wa.x, xv[r].x, a0[r]);
                a0[r] = fmaf(wa.y, xv[r].y, a0[r]);
                a0[r] = fmaf(wb.x, xv[r].z, a0[r]);
                a0[r] = fmaf(wb.y, xv[r].w, a0[r]);
            }
        }
        if (have1) {
            const float2 wa = *(const float2*)(W1 + k);
            const float2 wb = *(const float2*)(W1 + k + 2);
#pragma unroll
            for (int r = 0; r < ROWS; ++r) {
                a1[r] = fmaf(wa.x, xv[r].x, a1[r]);
                a1[r] = fmaf(wa.y, xv[r].y, a1[r]);
                a1[r] = fmaf(wb.x, xv[r].z, a1[r]);
                a1[r] = fmaf(wb.y, xv[r].w, a1[r]);
            }
        }
    }
    // tail (k = 688, 2 floats)
    {
        const float2 w0 = *(const float2*)(W0 + k);
        float2 w1m = make_float2(0.f, 0.f);
        if (have1) w1m = *(const float2*)(W1 + k);
#pragma unroll
        for (int r = 0; r < ROWS; ++r) {
            const float2 xv = *(const float2*)&sbuf[r * DP + k];
            a0[r] = fmaf(w0.x, xv.x, a0[r]);
            a0[r] = fmaf(w0.y, xv.y, a0[r]);
            a1[r] = fmaf(w1m.x, xv.x, a1[r]);
            a1[r] = fmaf(w1m.y, xv.y, a1[r]);
        }
    }

    // ---- exchange z through LDS (reuse sbuf) ----
    __syncthreads();   // everyone done reading x tile
    {
        const float b0 = (c0 < NTYPE) ? liner_b[c0] : 0.f;
#pragma unroll
        for (int r = 0; r < ROWS; ++r) sbuf[r * ZSTRIDE + c0] = a0[r] + b0;
        if (have1) {
            const float b1 = (c1 < NTYPE) ? liner_b[c1] : 0.f;
#pragma unroll
            for (int r = 0; r < ROWS; ++r) sbuf[r * ZSTRIDE + c1] = a1[r] + b1;
        }
    }
    __syncthreads();

    // ---- Phase C: per-row softmax / argmax / att / xr. wave w -> rows 4w..4w+3
    const int wave = tid >> 6;
    const int lane = tid & 63;
    for (int rr = 0; rr < 4; ++rr) {
        const int row  = wave * 4 + rr;
        const int grow = base + row;
        const float* zrow = &sbuf[row * ZSTRIDE];

        // max over 324
        float m = -INFINITY;
#pragma unroll
        for (int j = 0; j < 6; ++j) {
            const int c = lane + 64 * j;
            if (c < NTYPE) m = fmaxf(m, zrow[c]);
        }
#pragma unroll
        for (int off = 32; off; off >>= 1) m = fmaxf(m, __shfl_xor(m, off));

        // exp + sum
        float e[6];
        float s = 0.f;
#pragma unroll
        for (int j = 0; j < 6; ++j) {
            const int c = lane + 64 * j;
            e[j] = 0.f;
            if (c < NTYPE) { e[j] = __expf(zrow[c] - m); s += e[j]; }
        }
#pragma unroll
        for (int off = 32; off; off >>= 1) s += __shfl_xor(s, off);
        const float inv = 1.0f / s;      // == max(type_logits) exactly

        // write softmax row, scan nscore argmax (first-index tie-break)
        const int label = type_label[grow];
        float bestv = -INFINITY;
        int   besti = NTYPE;
#pragma unroll
        for (int j = 0; j < 6; ++j) {
            const int c = lane + 64 * j;
            if (c < NTYPE) {
                const float p = e[j] * inv;
                type_logits[(size_t)grow * NTYPE + c] = p;
                const float v = p + ((c == label) ? ALPHA * inv : 0.f);
                if (v > bestv || (v == bestv && c < besti)) { bestv = v; besti = c; }
            }
        }
#pragma unroll
        for (int off = 32; off; off >>= 1) {
            const float ov = __shfl_xor(bestv, off);
            const int   oi = __shfl_xor(besti, off);
            if (ov > bestv || (ov == bestv && oi < besti)) { bestv = ov; besti = oi; }
        }
        const int slabel = besti;

        const int q = query[grow];
        if (lane == 0)
            att[grow] = zrow[NTYPE + q] + table[slabel * NCLASS + q];
        if (lane < NCLASS)
            xr[(size_t)grow * NCLASS + lane] = zrow[NTYPE + lane];
    }
}

// ---------------------------------------------------------------------------
// Kernel 2: per-bag segment softmax over att + weighted sum of xr + bias
//   logits[b][c] = (sum_i exp(att_i - m) * xr[i][c]) / s + bias[c]
// one wave per bag.
// ---------------------------------------------------------------------------
__global__ __launch_bounds__(64) void k_bag(const float* __restrict__ att,
                                            const float* __restrict__ xr,
                                            const int* __restrict__ scope,
                                            const float* __restrict__ bias,
                                            float* __restrict__ logits) {
    const int b = blockIdx.x;
    const int lane = threadIdx.x;
    const int s0 = scope[b];
    const int s1 = scope[b + 1];

    float m = -INFINITY;
    for (int i = s0 + lane; i < s1; i += 64) m = fmaxf(m, att[i]);
#pragma unroll
    for (int off = 32; off; off >>= 1) m = fmaxf(m, __shfl_xor(m, off));

    float sum = 0.f;
    for (int i = s0 + lane; i < s1; i += 64) sum += __expf(att[i] - m);
#pragma unroll
    for (int off = 32; off; off >>= 1) sum += __shfl_xor(sum, off);
    const float inv = 1.0f / sum;

    float acc = 0.f;
    for (int i = s0; i < s1; ++i) {
        const float e = __expf(att[i] - m);     // uniform broadcast load
        if (lane < NCLASS) acc = fmaf(e, xr[(size_t)i * NCLASS + lane], acc);
    }
    if (lane < NCLASS) logits[b * NCLASS + lane] = acc * inv + bias[lane];
}

// ---------------------------------------------------------------------------
extern "C" void kernel_launch(void* const* d_in, const int* in_sizes, int n_in,
                              void* d_out, int out_size, void* d_ws, size_t ws_size,
                              hipStream_t stream) {
    const float* x          = (const float*)d_in[0];
    const int*   scope      = (const int*)d_in[1];
    const int*   type_label = (const int*)d_in[2];
    const int*   query      = (const int*)d_in[3];
    const float* rel_w      = (const float*)d_in[4];
    const float* type_w     = (const float*)d_in[5];
    const float* bias       = (const float*)d_in[6];
    const float* liner_w    = (const float*)d_in[7];
    const float* liner_b    = (const float*)d_in[8];

    float* logits      = (float*)d_out;                   // [8192 * 53]
    float* type_logits = (float*)d_out + NBAGS * NCLASS;  // [131072 * 324]

    float* ws    = (float*)d_ws;
    float* table = ws;                 // 324*53 = 17172 floats
    float* att   = ws + 17408;         // 131072 floats
    float* xr    = ws + 148480;        // 131072*53 floats

    hipLaunchKernelGGL(k_table, dim3((NTYPE * NCLASS + 3) / 4), dim3(256), 0, stream,
                       type_w, rel_w, table);
    hipLaunchKernelGGL(k_main, dim3(TOTAL / ROWS), dim3(256), 0, stream,
                       x, type_label, query, rel_w, liner_w, liner_b, table,
                       type_logits, att, xr);
    hipLaunchKernelGGL(k_bag, dim3(NBAGS), dim3(64), 0, stream,
                       att, xr, scope, bias, logits);
}